// Round 1
// baseline (258.030 us; speedup 1.0000x reference)
//
#include <hip/hip_runtime.h>

// RotaryEmbedding2D: out[b,s] is a 64x64 block-diagonal rotation matrix.
// B=16, S=1024, D=64, q=16, h=32. BASE=10000, SCALE=1.
// Row 2h:   col 2h = cos, col 2h+1 = -sin
// Row 2h+1: col 2h = sin, col 2h+1 =  cos
// 256 MiB fp32 output -> pure write-BW bound.
//
// Structure (v2): no LDS, no barrier. Each thread owns 4 float4 groups
// g = t + 256k (row = (t>>4)+16k, colgroup = t&15). The nonzero 8-byte pair
// of row r lives in colgroup r>>2, which maps bijectively to thread
// t = ((r&15)<<4)|(r>>2) at k* = r>>4. Equivalently: thread t has a nonzero
// group iff diff = (t&15)-(t>>6) is in {0,4,8,12}, at k* = diff>>2.
// Bulk zero stores carry no data dependency -> they issue immediately and
// saturate the store pipe; the exec-masked trig (16 lanes/wave) + single
// nonzero store hides underneath.

#define NBS 16384   // B*S

__global__ __launch_bounds__(256) void rope2d_kernel(
    const float* __restrict__ spa,   // (B,S,2)
    float* __restrict__ out)         // (B,S,64,64)
{
    const int bs = blockIdx.x;   // 0..16383
    const int t  = threadIdx.x;  // 0..255

    // Block-uniform -> compiler emits early s_load_dwordx2; latency hides
    // under the dependency-free zero stores below.
    const float xu = spa[bs * 2 + 0];
    const float yu = spa[bs * 2 + 1];

    const int  cg   = t & 15;          // colgroup (constant over k)
    const int  wq   = t >> 6;
    const int  diff = cg - wq;
    const bool has  = (diff >= 0) && ((diff & 3) == 0);
    const int  ks   = diff >> 2;       // valid only when has

    float4* __restrict__ outv = (float4*)out + (size_t)bs * 1024;
    const float4 z4 = make_float4(0.f, 0.f, 0.f, 0.f);

    // Bulk: stream zeros to every group this thread owns except its (single,
    // possible) nonzero group. No data dependency -> issues immediately.
    #pragma unroll
    for (int k = 0; k < 4; ++k) {
        if (!(has && k == ks))
            outv[t + k * 256] = z4;
    }

    // Sparse: the one nonzero group (16 lanes per wave, exec-masked).
    if (has) {
        const int row = (t >> 4) + (ks << 4);   // 0..63
        const int h   = row >> 1;               // 0..31
        const float xy   = (h & 16) ? yu : xu;
        // inv_freq = 10000^(-(h%16)/16) = exp2(-(h%16) * log2(10000)/16)
        const float invf = exp2f(-(float)(h & 15) * 0.83048202372184059f);
        const float a = xy * invf;
        const float s = sinf(a);
        const float c = cosf(a);
        float e0, e1;
        if (row & 1) { e0 = s; e1 = c; }        // odd row:  sin, cos
        else         { e0 = c; e1 = -s; }       // even row: cos, -sin
        float4 v;
        if (row & 2) v = make_float4(0.f, 0.f, e0, e1);  // pair at offset 2
        else         v = make_float4(e0, e1, 0.f, 0.f);  // pair at offset 0
        outv[t + ks * 256] = v;
    }
}

extern "C" void kernel_launch(void* const* d_in, const int* in_sizes, int n_in,
                              void* d_out, int out_size, void* d_ws, size_t ws_size,
                              hipStream_t stream) {
    const float* spa = (const float*)d_in[0];
    float* out = (float*)d_out;
    rope2d_kernel<<<NBS, 256, 0, stream>>>(spa, out);
}